// Round 3
// baseline (16319.617 us; speedup 1.0000x reference)
//
#include <hip/hip_runtime.h>

// ---------- types ----------
typedef __bf16 bf16x8 __attribute__((ext_vector_type(8)));
typedef float  f32x4  __attribute__((ext_vector_type(4)));

#define LDA 136  // padded bf16 row stride for LDS tiles (breaks bank conflicts)

static __device__ __forceinline__ unsigned short f2bf(float f) {
  // round-to-nearest-even fp32 -> bf16 bits (inputs are finite)
  unsigned int u = __float_as_uint(f);
  u += 0x7fffu + ((u >> 16) & 1u);
  return (unsigned short)(u >> 16);
}

// ---------- zero the 256-float stats buffer (avoid hipMemsetAsync in capture) ----
__global__ void zero256(float* __restrict__ p) { p[threadIdx.x] = 0.f; }

// ---------- elementwise: agg = x (self term, layer 1) ----------
__global__ void copy_k(const float* __restrict__ src, float* __restrict__ dst,
                       long long n) {
  long long i = ((long long)blockIdx.x * blockDim.x + threadIdx.x) * 4;
  if (i < n) *(float4*)(dst + i) = *(const float4*)(src + i);
}

// ---------- scatter: agg[dst] += feat[src]  (layer 1, raw features) ----------
// NOTE: harness passes integer inputs as int32 (NOT int64 like the reference).
__global__ void edge_scatter(const float* __restrict__ feat,
                             const int* __restrict__ ei,
                             float* __restrict__ agg, long long E) {
  long long tid = (long long)blockIdx.x * blockDim.x + threadIdx.x;
  if (tid >= E * 32) return;
  long long e = tid >> 5;
  int c = (int)(tid & 31) << 2;
  int s = ei[e];
  int d = ei[E + e];
  float4 v = *(const float4*)(feat + (long long)s * 128 + c);
  float* p = agg + (long long)d * 128 + c;
  atomicAdd(p + 0, v.x);
  atomicAdd(p + 1, v.y);
  atomicAdd(p + 2, v.z);
  atomicAdd(p + 3, v.w);
}

// ---------- scatter with fused BN-affine + ReLU on the gathered value ----------
__global__ void edge_scatter_affine(const float* __restrict__ h,
                                    const int* __restrict__ ei,
                                    const float* __restrict__ coeff,
                                    float* __restrict__ agg, long long E) {
  long long tid = (long long)blockIdx.x * blockDim.x + threadIdx.x;
  if (tid >= E * 32) return;
  long long e = tid >> 5;
  int c = (int)(tid & 31) << 2;
  int s = ei[e];
  int d = ei[E + e];
  float4 v  = *(const float4*)(h + (long long)s * 128 + c);
  float4 sc = *(const float4*)(coeff + c);
  float4 sh = *(const float4*)(coeff + 128 + c);
  float4 o;
  o.x = fmaxf(fmaf(v.x, sc.x, sh.x), 0.f);
  o.y = fmaxf(fmaf(v.y, sc.y, sh.y), 0.f);
  o.z = fmaxf(fmaf(v.z, sc.z, sh.z), 0.f);
  o.w = fmaxf(fmaf(v.w, sc.w, sh.w), 0.f);
  float* p = agg + (long long)d * 128 + c;
  atomicAdd(p + 0, o.x);
  atomicAdd(p + 1, o.y);
  atomicAdd(p + 2, o.z);
  atomicAdd(p + 3, o.w);
}

// ---------- elementwise: agg = relu(h*scale+shift)  (self term, layers 2/3) ----------
__global__ void apply_affine(const float* __restrict__ h,
                             const float* __restrict__ coeff,
                             float* __restrict__ agg, long long N) {
  long long tid = (long long)blockIdx.x * blockDim.x + threadIdx.x;
  if (tid >= N * 32) return;
  long long row = tid >> 5;
  int c = (int)(tid & 31) << 2;
  float4 v  = *(const float4*)(h + row * 128 + c);
  float4 sc = *(const float4*)(coeff + c);
  float4 sh = *(const float4*)(coeff + 128 + c);
  float4 o;
  o.x = fmaxf(fmaf(v.x, sc.x, sh.x), 0.f);
  o.y = fmaxf(fmaf(v.y, sc.y, sh.y), 0.f);
  o.z = fmaxf(fmaf(v.z, sc.z, sh.z), 0.f);
  o.w = fmaxf(fmaf(v.w, sc.w, sh.w), 0.f);
  *(float4*)(agg + row * 128 + c) = o;
}

// ---------- column stats: stats[0:128]=sum, stats[128:256]=sumsq ----------
__global__ void stats128(const float* __restrict__ h, float* __restrict__ stats,
                         int M) {
  int f = threadIdx.x & 127;
  int rg = threadIdx.x >> 7;  // 0 or 1
  float s = 0.f, sq = 0.f;
  for (long long r = (long long)blockIdx.x * 2 + rg; r < M;
       r += (long long)gridDim.x * 2) {
    float v = h[r * 128 + f];
    s += v;
    sq += v * v;
  }
  __shared__ float ls[256], lq[256];
  ls[threadIdx.x] = s;
  lq[threadIdx.x] = sq;
  __syncthreads();
  if (rg == 0) {
    s += ls[threadIdx.x + 128];
    sq += lq[threadIdx.x + 128];
    atomicAdd(&stats[f], s);
    atomicAdd(&stats[128 + f], sq);
  }
}

// ---------- BN coefficients: scale = g*rsqrt(var+eps), shift = be - mean*scale ----------
__global__ void bn_coeffs(const float* __restrict__ stats,
                          const float* __restrict__ g,
                          const float* __restrict__ be,
                          float* __restrict__ coeff, float invN) {
  int f = threadIdx.x;
  float mean = stats[f] * invN;
  float var = stats[128 + f] * invN - mean * mean;
  float sc = g[f] * rsqrtf(var + 1e-5f);
  coeff[f] = sc;
  coeff[128 + f] = be[f] - mean * sc;
}

// ---------- GEMM: Hout[M,128] = bf16(A[M,128]) @ bf16(W[128,128])^T + bias ----------
__global__ void __launch_bounds__(256)
gemm128(const float* __restrict__ A, const float* __restrict__ W,
        const float* __restrict__ bias, float* __restrict__ Hout, int M) {
  __shared__ __align__(16) unsigned short sA[128 * LDA];
  __shared__ __align__(16) unsigned short sB[128 * LDA];
  const int tid = threadIdx.x;
  const int row0 = blockIdx.x * 128;

  // stage A tile (fp32 -> bf16), 256 threads x 16 iters x float4
  for (int j = 0; j < 16; ++j) {
    int flat = j * 1024 + tid * 4;
    int r = flat >> 7, c = flat & 127;
    int gr = row0 + r;
    float4 v = make_float4(0.f, 0.f, 0.f, 0.f);
    if (gr < M) v = *(const float4*)(A + (long long)gr * 128 + c);
    unsigned short* p = sA + r * LDA + c;
    p[0] = f2bf(v.x); p[1] = f2bf(v.y); p[2] = f2bf(v.z); p[3] = f2bf(v.w);
  }
  // stage W (row-major [out][k] == B^T, ideal layout)
  for (int j = 0; j < 16; ++j) {
    int flat = j * 1024 + tid * 4;
    int r = flat >> 7, c = flat & 127;
    float4 v = *(const float4*)(W + r * 128 + c);
    unsigned short* p = sB + r * LDA + c;
    p[0] = f2bf(v.x); p[1] = f2bf(v.y); p[2] = f2bf(v.z); p[3] = f2bf(v.w);
  }
  __syncthreads();

  const int lane = tid & 63, wid = tid >> 6;
  const int wM = (wid >> 1) * 64, wN = (wid & 1) * 64;
  const int l15 = lane & 15, quad = lane >> 4;
  f32x4 acc[4][4] = {};

  for (int kk = 0; kk < 4; ++kk) {
    const int kb = kk * 32 + quad * 8;
    bf16x8 af[4], bfr[4];
    for (int mi = 0; mi < 4; ++mi)
      af[mi] = *reinterpret_cast<const bf16x8*>(sA + (wM + mi * 16 + l15) * LDA + kb);
    for (int ni = 0; ni < 4; ++ni)
      bfr[ni] = *reinterpret_cast<const bf16x8*>(sB + (wN + ni * 16 + l15) * LDA + kb);
    for (int mi = 0; mi < 4; ++mi)
      for (int ni = 0; ni < 4; ++ni)
        acc[mi][ni] = __builtin_amdgcn_mfma_f32_16x16x32_bf16(
            af[mi], bfr[ni], acc[mi][ni], 0, 0, 0);
  }

  for (int mi = 0; mi < 4; ++mi) {
    for (int ni = 0; ni < 4; ++ni) {
      int col = wN + ni * 16 + l15;
      float bv = bias[col];
      for (int r = 0; r < 4; ++r) {
        int grow = row0 + wM + mi * 16 + quad * 4 + r;
        if (grow < M)
          Hout[(long long)grow * 128 + col] = acc[mi][ni][r] + bv;
      }
    }
  }
}

// ---------- final GEMM: Out[M,10] = bf16(A[M,128]) @ bf16(W3[10,128])^T + b3 ----------
__global__ void __launch_bounds__(256)
gemm_out(const float* __restrict__ A, const float* __restrict__ W3,
         const float* __restrict__ b3, float* __restrict__ Out, int M) {
  __shared__ __align__(16) unsigned short sA[128 * LDA];
  __shared__ __align__(16) unsigned short sB[16 * LDA];
  const int tid = threadIdx.x;
  const int row0 = blockIdx.x * 128;

  for (int j = 0; j < 16; ++j) {
    int flat = j * 1024 + tid * 4;
    int r = flat >> 7, c = flat & 127;
    int gr = row0 + r;
    float4 v = make_float4(0.f, 0.f, 0.f, 0.f);
    if (gr < M) v = *(const float4*)(A + (long long)gr * 128 + c);
    unsigned short* p = sA + r * LDA + c;
    p[0] = f2bf(v.x); p[1] = f2bf(v.y); p[2] = f2bf(v.z); p[3] = f2bf(v.w);
  }
  for (int j = 0; j < 2; ++j) {
    int flat = j * 1024 + tid * 4;
    int r = flat >> 7, c = flat & 127;
    float4 v = make_float4(0.f, 0.f, 0.f, 0.f);
    if (r < 10) v = *(const float4*)(W3 + r * 128 + c);
    unsigned short* p = sB + r * LDA + c;
    p[0] = f2bf(v.x); p[1] = f2bf(v.y); p[2] = f2bf(v.z); p[3] = f2bf(v.w);
  }
  __syncthreads();

  const int lane = tid & 63, wid = tid >> 6;
  const int l15 = lane & 15, quad = lane >> 4;
  f32x4 acc[2] = {};
  for (int kk = 0; kk < 4; ++kk) {
    const int kb = kk * 32 + quad * 8;
    bf16x8 b = *reinterpret_cast<const bf16x8*>(sB + l15 * LDA + kb);
    for (int mi = 0; mi < 2; ++mi) {
      bf16x8 a = *reinterpret_cast<const bf16x8*>(
          sA + (wid * 32 + mi * 16 + l15) * LDA + kb);
      acc[mi] = __builtin_amdgcn_mfma_f32_16x16x32_bf16(a, b, acc[mi], 0, 0, 0);
    }
  }
  if (l15 < 10) {
    float bv = b3[l15];
    for (int mi = 0; mi < 2; ++mi)
      for (int r = 0; r < 4; ++r) {
        int grow = row0 + wid * 32 + mi * 16 + quad * 4 + r;
        if (grow < M) Out[(long long)grow * 10 + l15] = acc[mi][r] + bv;
      }
  }
}

// ---------- host ----------
extern "C" void kernel_launch(void* const* d_in, const int* in_sizes, int n_in,
                              void* d_out, int out_size, void* d_ws,
                              size_t ws_size, hipStream_t stream) {
  const float* x      = (const float*)d_in[0];
  const int*   ei     = (const int*)d_in[1];  // int32 per harness contract
  const float* W1 = (const float*)d_in[2];
  const float* b1 = (const float*)d_in[3];
  const float* g1 = (const float*)d_in[4];
  const float* be1 = (const float*)d_in[5];
  const float* W2 = (const float*)d_in[6];
  const float* b2 = (const float*)d_in[7];
  const float* g2 = (const float*)d_in[8];
  const float* be2 = (const float*)d_in[9];
  const float* W3 = (const float*)d_in[10];
  const float* b3 = (const float*)d_in[11];

  const long long N = in_sizes[0] / 128;
  const long long E = in_sizes[1] / 2;

  float* buf0  = (float*)d_ws;        // agg buffer  (N*128 fp32)
  float* buf1  = buf0 + N * 128;      // h buffer    (N*128 fp32)
  float* stats = buf1 + N * 128;      // 256 floats
  float* coeff = stats + 256;         // 256 floats
  float* out   = (float*)d_out;

  const int TPB = 256;
  const int applyBlocks = (int)((N * 32 + TPB - 1) / TPB);
  const int edgeBlocks  = (int)((E * 32 + TPB - 1) / TPB);
  const int gemmBlocks  = (int)((N + 127) / 128);
  const float invN = 1.0f / (float)N;

  // ---- layer 1 ----
  copy_k<<<applyBlocks, TPB, 0, stream>>>(x, buf0, N * 128);
  edge_scatter<<<edgeBlocks, TPB, 0, stream>>>(x, ei, buf0, E);
  gemm128<<<gemmBlocks, TPB, 0, stream>>>(buf0, W1, b1, buf1, (int)N);
  zero256<<<1, 256, 0, stream>>>(stats);
  stats128<<<512, TPB, 0, stream>>>(buf1, stats, (int)N);
  bn_coeffs<<<1, 128, 0, stream>>>(stats, g1, be1, coeff, invN);

  // ---- layer 2 (BN1+ReLU fused into self-init and gather) ----
  apply_affine<<<applyBlocks, TPB, 0, stream>>>(buf1, coeff, buf0, N);
  edge_scatter_affine<<<edgeBlocks, TPB, 0, stream>>>(buf1, ei, coeff, buf0, E);
  gemm128<<<gemmBlocks, TPB, 0, stream>>>(buf0, W2, b2, buf1, (int)N);
  zero256<<<1, 256, 0, stream>>>(stats);
  stats128<<<512, TPB, 0, stream>>>(buf1, stats, (int)N);
  bn_coeffs<<<1, 128, 0, stream>>>(stats, g2, be2, coeff, invN);

  // ---- layer 3 ----
  apply_affine<<<applyBlocks, TPB, 0, stream>>>(buf1, coeff, buf0, N);
  edge_scatter_affine<<<edgeBlocks, TPB, 0, stream>>>(buf1, ei, coeff, buf0, E);
  gemm_out<<<gemmBlocks, TPB, 0, stream>>>(buf0, W3, b3, out, (int)N);
}

// Round 4
// 1343.173 us; speedup vs baseline: 12.1500x; 12.1500x over previous
//
#include <hip/hip_runtime.h>

// ---------- types ----------
typedef __bf16 bf16x8 __attribute__((ext_vector_type(8)));
typedef float  f32x4  __attribute__((ext_vector_type(4)));

#define LDA 136  // padded bf16 row stride for LDS tiles (breaks bank conflicts)

static __device__ __forceinline__ unsigned short f2bf(float f) {
  unsigned int u = __float_as_uint(f);
  u += 0x7fffu + ((u >> 16) & 1u);
  return (unsigned short)(u >> 16);
}

// ---------- tiny utility kernels ----------
__global__ void zero256(float* __restrict__ p) { p[threadIdx.x] = 0.f; }

__global__ void zero_int(int* __restrict__ p, int n) {
  int i = blockIdx.x * blockDim.x + threadIdx.x;
  if (i < n) p[i] = 0;
}

__global__ void copy_int(const int* __restrict__ s, int* __restrict__ d, int n) {
  int i = blockIdx.x * blockDim.x + threadIdx.x;
  if (i < n) d[i] = s[i];
}

// ---------- CSR build: degree count ----------
__global__ void count_deg(const int* __restrict__ ei, int* __restrict__ deg,
                          int E) {
  int e = blockIdx.x * blockDim.x + threadIdx.x;
  if (e < E) atomicAdd(&deg[ei[E + e]], 1);  // dst = ei[E+e]
}

// ---------- CSR build: single-block inclusive scan -> row_start[1..N] ----------
__global__ void scan_deg(const int* __restrict__ deg, int* __restrict__ rs,
                         int n) {
  __shared__ int tmp[1024];
  __shared__ int carry;
  if (threadIdx.x == 0) { carry = 0; rs[0] = 0; }
  __syncthreads();
  for (int base = 0; base < n; base += 1024) {
    int i = base + (int)threadIdx.x;
    int v = (i < n) ? deg[i] : 0;
    tmp[threadIdx.x] = v;
    __syncthreads();
    for (int off = 1; off < 1024; off <<= 1) {
      int t = (threadIdx.x >= (unsigned)off) ? tmp[threadIdx.x - off] : 0;
      __syncthreads();
      tmp[threadIdx.x] += t;
      __syncthreads();
    }
    if (i < n) rs[i + 1] = tmp[threadIdx.x] + carry;
    __syncthreads();
    if (threadIdx.x == 0) carry += tmp[1023];
    __syncthreads();
  }
}

// ---------- CSR build: scatter src indices into slots ----------
__global__ void fill_csr(const int* __restrict__ ei, int* __restrict__ cursor,
                         int* __restrict__ csr, int E) {
  int e = blockIdx.x * blockDim.x + threadIdx.x;
  if (e < E) {
    int d = ei[E + e];
    int slot = atomicAdd(&cursor[d], 1);
    csr[slot] = ei[e];  // src
  }
}

// ---------- aggregation: agg[i] = t[i] + sum_{j in N(i)} t[j], 128 features ----
// one wave per node, lane -> float2 (128 floats = 512B coalesced per row)
__global__ void __launch_bounds__(256)
csr_agg128(const float* __restrict__ t, const int* __restrict__ rs,
           const int* __restrict__ csr, float* __restrict__ agg, int N) {
  int node = blockIdx.x * 4 + (threadIdx.x >> 6);
  if (node >= N) return;
  int c = (threadIdx.x & 63) * 2;
  const float* base = t + node * 128 + c;
  float2 acc = *(const float2*)base;  // self term
  int b = rs[node], e = rs[node + 1];
  int i = b;
  for (; i + 3 < e; i += 4) {
    int j0 = csr[i], j1 = csr[i + 1], j2 = csr[i + 2], j3 = csr[i + 3];
    float2 v0 = *(const float2*)(t + j0 * 128 + c);
    float2 v1 = *(const float2*)(t + j1 * 128 + c);
    float2 v2 = *(const float2*)(t + j2 * 128 + c);
    float2 v3 = *(const float2*)(t + j3 * 128 + c);
    acc.x += v0.x + v1.x + v2.x + v3.x;
    acc.y += v0.y + v1.y + v2.y + v3.y;
  }
  for (; i < e; ++i) {
    int j = csr[i];
    float2 v = *(const float2*)(t + j * 128 + c);
    acc.x += v.x;
    acc.y += v.y;
  }
  *(float2*)(agg + node * 128 + c) = acc;
}

// ---------- aggregation on 10-dim (stride 16) + bias -> out[N,10] ----------
__global__ void __launch_bounds__(256)
csr_agg10(const float* __restrict__ y, const int* __restrict__ rs,
          const int* __restrict__ csr, const float* __restrict__ b3,
          float* __restrict__ out, int N) {
  int t = blockIdx.x * blockDim.x + threadIdx.x;
  int node = t >> 4;
  int f = t & 15;
  if (node >= N) return;
  bool act = f < 10;
  float acc = act ? y[node * 16 + f] : 0.f;
  int b = rs[node], e = rs[node + 1];
  int i = b;
  for (; i + 3 < e; i += 4) {
    int j0 = csr[i], j1 = csr[i + 1], j2 = csr[i + 2], j3 = csr[i + 3];
    if (act)
      acc += y[j0 * 16 + f] + y[j1 * 16 + f] + y[j2 * 16 + f] + y[j3 * 16 + f];
  }
  for (; i < e; ++i) {
    int j = csr[i];
    if (act) acc += y[j * 16 + f];
  }
  if (act) out[node * 10 + f] = acc + b3[f];
}

// ---------- elementwise in-place: h = relu(h*scale+shift) ----------
__global__ void apply_affine(float* __restrict__ h,
                             const float* __restrict__ coeff, long long N) {
  long long tid = (long long)blockIdx.x * blockDim.x + threadIdx.x;
  if (tid >= N * 32) return;
  int row = (int)(tid >> 5);
  int c = (int)(tid & 31) << 2;
  float4 v = *(const float4*)(h + row * 128 + c);
  float4 sc = *(const float4*)(coeff + c);
  float4 sh = *(const float4*)(coeff + 128 + c);
  float4 o;
  o.x = fmaxf(fmaf(v.x, sc.x, sh.x), 0.f);
  o.y = fmaxf(fmaf(v.y, sc.y, sh.y), 0.f);
  o.z = fmaxf(fmaf(v.z, sc.z, sh.z), 0.f);
  o.w = fmaxf(fmaf(v.w, sc.w, sh.w), 0.f);
  *(float4*)(h + row * 128 + c) = o;
}

// ---------- column stats: stats[0:128]=sum, stats[128:256]=sumsq ----------
__global__ void stats128(const float* __restrict__ h, float* __restrict__ stats,
                         int M) {
  int f = threadIdx.x & 127;
  int rg = threadIdx.x >> 7;
  float s = 0.f, sq = 0.f;
  for (int r = blockIdx.x * 2 + rg; r < M; r += gridDim.x * 2) {
    float v = h[r * 128 + f];
    s += v;
    sq += v * v;
  }
  __shared__ float ls[256], lq[256];
  ls[threadIdx.x] = s;
  lq[threadIdx.x] = sq;
  __syncthreads();
  if (rg == 0) {
    s += ls[threadIdx.x + 128];
    sq += lq[threadIdx.x + 128];
    atomicAdd(&stats[f], s);
    atomicAdd(&stats[128 + f], sq);
  }
}

// ---------- BN coefficients ----------
__global__ void bn_coeffs(const float* __restrict__ stats,
                          const float* __restrict__ g,
                          const float* __restrict__ be,
                          float* __restrict__ coeff, float invN) {
  int f = threadIdx.x;
  float mean = stats[f] * invN;
  float var = stats[128 + f] * invN - mean * mean;
  float sc = g[f] * rsqrtf(var + 1e-5f);
  coeff[f] = sc;
  coeff[128 + f] = be[f] - mean * sc;
}

// ---------- GEMM: Hout[M,128] = bf16(A[M,128]) @ bf16(W[128,128])^T + bias ----------
__global__ void __launch_bounds__(256)
gemm128(const float* __restrict__ A, const float* __restrict__ W,
        const float* __restrict__ bias, float* __restrict__ Hout, int M) {
  __shared__ __align__(16) unsigned short sA[128 * LDA];
  __shared__ __align__(16) unsigned short sB[128 * LDA];
  const int tid = threadIdx.x;
  const int row0 = blockIdx.x * 128;

  for (int j = 0; j < 16; ++j) {
    int flat = j * 1024 + tid * 4;
    int r = flat >> 7, c = flat & 127;
    int gr = row0 + r;
    float4 v = make_float4(0.f, 0.f, 0.f, 0.f);
    if (gr < M) v = *(const float4*)(A + gr * 128 + c);
    unsigned short* p = sA + r * LDA + c;
    p[0] = f2bf(v.x); p[1] = f2bf(v.y); p[2] = f2bf(v.z); p[3] = f2bf(v.w);
  }
  for (int j = 0; j < 16; ++j) {
    int flat = j * 1024 + tid * 4;
    int r = flat >> 7, c = flat & 127;
    float4 v = *(const float4*)(W + r * 128 + c);
    unsigned short* p = sB + r * LDA + c;
    p[0] = f2bf(v.x); p[1] = f2bf(v.y); p[2] = f2bf(v.z); p[3] = f2bf(v.w);
  }
  __syncthreads();

  const int lane = tid & 63, wid = tid >> 6;
  const int wM = (wid >> 1) * 64, wN = (wid & 1) * 64;
  const int l15 = lane & 15, quad = lane >> 4;
  f32x4 acc[4][4] = {};

  for (int kk = 0; kk < 4; ++kk) {
    const int kb = kk * 32 + quad * 8;
    bf16x8 af[4], bfr[4];
    for (int mi = 0; mi < 4; ++mi)
      af[mi] = *reinterpret_cast<const bf16x8*>(sA + (wM + mi * 16 + l15) * LDA + kb);
    for (int ni = 0; ni < 4; ++ni)
      bfr[ni] = *reinterpret_cast<const bf16x8*>(sB + (wN + ni * 16 + l15) * LDA + kb);
    for (int mi = 0; mi < 4; ++mi)
      for (int ni = 0; ni < 4; ++ni)
        acc[mi][ni] = __builtin_amdgcn_mfma_f32_16x16x32_bf16(
            af[mi], bfr[ni], acc[mi][ni], 0, 0, 0);
  }

  for (int mi = 0; mi < 4; ++mi) {
    for (int ni = 0; ni < 4; ++ni) {
      int col = wN + ni * 16 + l15;
      float bv = bias[col];
      for (int r = 0; r < 4; ++r) {
        int grow = row0 + wM + mi * 16 + quad * 4 + r;
        if (grow < M) Hout[grow * 128 + col] = acc[mi][ni][r] + bv;
      }
    }
  }
}

// ---------- y[M,16(10 used)] = bf16(A[M,128]) @ bf16(W3[10,128])^T  (no bias) ----
__global__ void __launch_bounds__(256)
gemm_y(const float* __restrict__ A, const float* __restrict__ W3,
       float* __restrict__ Y, int M) {
  __shared__ __align__(16) unsigned short sA[128 * LDA];
  __shared__ __align__(16) unsigned short sB[16 * LDA];
  const int tid = threadIdx.x;
  const int row0 = blockIdx.x * 128;

  for (int j = 0; j < 16; ++j) {
    int flat = j * 1024 + tid * 4;
    int r = flat >> 7, c = flat & 127;
    int gr = row0 + r;
    float4 v = make_float4(0.f, 0.f, 0.f, 0.f);
    if (gr < M) v = *(const float4*)(A + gr * 128 + c);
    unsigned short* p = sA + r * LDA + c;
    p[0] = f2bf(v.x); p[1] = f2bf(v.y); p[2] = f2bf(v.z); p[3] = f2bf(v.w);
  }
  for (int j = 0; j < 2; ++j) {
    int flat = j * 1024 + tid * 4;
    int r = flat >> 7, c = flat & 127;
    float4 v = make_float4(0.f, 0.f, 0.f, 0.f);
    if (r < 10) v = *(const float4*)(W3 + r * 128 + c);
    unsigned short* p = sB + r * LDA + c;
    p[0] = f2bf(v.x); p[1] = f2bf(v.y); p[2] = f2bf(v.z); p[3] = f2bf(v.w);
  }
  __syncthreads();

  const int lane = tid & 63, wid = tid >> 6;
  const int l15 = lane & 15, quad = lane >> 4;
  f32x4 acc[2] = {};
  for (int kk = 0; kk < 4; ++kk) {
    const int kb = kk * 32 + quad * 8;
    bf16x8 b = *reinterpret_cast<const bf16x8*>(sB + l15 * LDA + kb);
    for (int mi = 0; mi < 2; ++mi) {
      bf16x8 a = *reinterpret_cast<const bf16x8*>(
          sA + (wid * 32 + mi * 16 + l15) * LDA + kb);
      acc[mi] = __builtin_amdgcn_mfma_f32_16x16x32_bf16(a, b, acc[mi], 0, 0, 0);
    }
  }
  if (l15 < 10) {
    for (int mi = 0; mi < 2; ++mi)
      for (int r = 0; r < 4; ++r) {
        int grow = row0 + wid * 32 + mi * 16 + quad * 4 + r;
        if (grow < M) Y[grow * 16 + l15] = acc[mi][r];
      }
  }
}

// ---------- host ----------
extern "C" void kernel_launch(void* const* d_in, const int* in_sizes, int n_in,
                              void* d_out, int out_size, void* d_ws,
                              size_t ws_size, hipStream_t stream) {
  const float* x  = (const float*)d_in[0];
  const int*   ei = (const int*)d_in[1];  // int32 per harness contract
  const float* W1 = (const float*)d_in[2];
  const float* b1 = (const float*)d_in[3];
  const float* g1 = (const float*)d_in[4];
  const float* be1 = (const float*)d_in[5];
  const float* W2 = (const float*)d_in[6];
  const float* b2 = (const float*)d_in[7];
  const float* g2 = (const float*)d_in[8];
  const float* be2 = (const float*)d_in[9];
  const float* W3 = (const float*)d_in[10];
  const float* b3 = (const float*)d_in[11];

  const int N = in_sizes[0] / 128;
  const int E = in_sizes[1] / 2;

  float* buf0  = (float*)d_ws;         // agg buffer  (N*128 f32)
  float* buf1  = buf0 + (size_t)N * 128;  // h buffer (N*128 f32)
  float* ybuf  = buf1 + (size_t)N * 128;  // N*16 f32
  float* stats = ybuf + (size_t)N * 16;   // 256 f32
  float* coeff = stats + 256;             // 256 f32
  int* deg    = (int*)(coeff + 256);      // N ints (doubles as cursor)
  int* rs     = deg + N;                  // N+1 ints
  int* csr    = rs + N + 1;               // E ints
  float* out  = (float*)d_out;

  const int TPB = 256;
  const int nBlocksN  = (N + TPB - 1) / TPB;
  const int nBlocksE  = (E + TPB - 1) / TPB;
  const int applyBlocks = (int)(((long long)N * 32 + TPB - 1) / TPB);
  const int aggBlocks  = (N + 3) / 4;          // 4 nodes per 256-thr block
  const int agg10Blocks = (N * 16 + TPB - 1) / TPB;
  const int gemmBlocks = (N + 127) / 128;
  const float invN = 1.0f / (float)N;

  // ---- CSR build (once; shared by all 3 layers) ----
  zero_int<<<nBlocksN, TPB, 0, stream>>>(deg, N);
  count_deg<<<nBlocksE, TPB, 0, stream>>>(ei, deg, E);
  scan_deg<<<1, 1024, 0, stream>>>(deg, rs, N);
  copy_int<<<nBlocksN, TPB, 0, stream>>>(rs, deg, N);  // deg -> cursor
  fill_csr<<<nBlocksE, TPB, 0, stream>>>(ei, deg, csr, E);

  // ---- layer 1 ----
  csr_agg128<<<aggBlocks, TPB, 0, stream>>>(x, rs, csr, buf0, N);
  gemm128<<<gemmBlocks, TPB, 0, stream>>>(buf0, W1, b1, buf1, N);
  zero256<<<1, 256, 0, stream>>>(stats);
  stats128<<<512, TPB, 0, stream>>>(buf1, stats, N);
  bn_coeffs<<<1, 128, 0, stream>>>(stats, g1, be1, coeff, invN);

  // ---- layer 2 ----
  apply_affine<<<applyBlocks, TPB, 0, stream>>>(buf1, coeff, N);
  csr_agg128<<<aggBlocks, TPB, 0, stream>>>(buf1, rs, csr, buf0, N);
  gemm128<<<gemmBlocks, TPB, 0, stream>>>(buf0, W2, b2, buf1, N);
  zero256<<<1, 256, 0, stream>>>(stats);
  stats128<<<512, TPB, 0, stream>>>(buf1, stats, N);
  bn_coeffs<<<1, 128, 0, stream>>>(stats, g2, be2, coeff, invN);

  // ---- layer 3 (aggregate AFTER the GEMM: 10-dim instead of 128-dim) ----
  apply_affine<<<applyBlocks, TPB, 0, stream>>>(buf1, coeff, N);
  gemm_y<<<gemmBlocks, TPB, 0, stream>>>(buf1, W3, ybuf, N);
  csr_agg10<<<agg10Blocks, TPB, 0, stream>>>(ybuf, rs, csr, b3, out, N);
}